// Round 7
// baseline (370.940 us; speedup 1.0000x reference)
//
#include <hip/hip_runtime.h>

typedef __bf16 bf16x8 __attribute__((ext_vector_type(8)));
typedef float floatx4 __attribute__((ext_vector_type(4)));
typedef unsigned short ushort8 __attribute__((ext_vector_type(8)));

__device__ __forceinline__ unsigned short f2bf(float f) {
    unsigned u = __float_as_uint(f);
    u += 0x7fffu + ((u >> 16) & 1u);   // round-to-nearest-even
    return (unsigned short)(u >> 16);
}

// ---------------------------------------------------------------------------
// Circuit helpers (unchanged, proven). State split 8-way.
// ---------------------------------------------------------------------------
template <int ST>   // ST in {4,2,1}: thread-local gate
__device__ __forceinline__ void apply_local(float* fr, float* fi,
    float m00r, float m00i, float m01r, float m01i,
    float m10r, float m10i, float m11r, float m11i) {
#pragma unroll
    for (int i = 0; i < 8; ++i) {
        if ((i & ST) == 0) {
            int i1 = i + ST;
            float r0 = fr[i], u0 = fi[i], r1 = fr[i1], u1 = fi[i1];
            fr[i]  = m00r * r0 - m00i * u0 + m01r * r1 - m01i * u1;
            fi[i]  = m00r * u0 + m00i * r0 + m01r * u1 + m01i * r1;
            fr[i1] = m10r * r0 - m10i * u0 + m11r * r1 - m11i * u1;
            fi[i1] = m10r * u0 + m10i * r0 + m11r * u1 + m11i * r1;
        }
    }
}

template <int XM>   // XM in {32,16,8}: cross-thread gate; hi = bit=1 side
__device__ __forceinline__ void apply_cross(float* fr, float* fi, bool hi,
    float m00r, float m00i, float m01r, float m01i,
    float m10r, float m10i, float m11r, float m11i) {
    float car = hi ? m10r : m00r, cai = hi ? m10i : m00i;
    float cbr = hi ? m11r : m01r, cbi = hi ? m11i : m01i;
#pragma unroll
    for (int j = 0; j < 8; ++j) {
        float mr = fr[j], mi = fi[j];
        float pr = __shfl_xor(mr, XM);
        float pi = __shfl_xor(mi, XM);
        float a0r = hi ? pr : mr, a0i = hi ? pi : mi;
        float a1r = hi ? mr : pr, a1i = hi ? mi : pi;
        fr[j] = car * a0r - cai * a0i + cbr * a1r - cbi * a1i;
        fi[j] = car * a0i + cai * a0r + cbr * a1i + cbi * a1r;
    }
}

#define SWAP2(a, b) { float _t = fr[a]; fr[a] = fr[b]; fr[b] = _t; \
                      _t = fi[a]; fi[a] = fi[b]; fi[b] = _t; }

// ---------------------------------------------------------------------------
// K0: prep — transpose head_w2 [128][1296] fp32 -> w2t [1296][128] bf16.
// ---------------------------------------------------------------------------
__global__ __launch_bounds__(512) void prep_kernel(
    const float* __restrict__ hw2, unsigned short* __restrict__ w2t) {
    int t = blockIdx.x * 512 + threadIdx.x;   // 41*512 = 20992 >= 20736
    int nn = t >> 4;
    int kc = (t & 15) * 8;
    if (nn < 1296) {
        ushort8 pk;
#pragma unroll
        for (int j = 0; j < 8; ++j) pk[j] = f2bf(hw2[(size_t)(kc + j) * 1296 + nn]);
        *(ushort8*)(w2t + (size_t)nn * 128 + kc) = pk;
    }
}

// ---------------------------------------------------------------------------
// K1: front — R6 mega phases 0-4 verbatim; g -> GLOBAL (coalesced, 2 KB per
// wave store-inst). Split from the GEMM so rocprof attributes the stall:
// this kernel is the enc+circuit+g cost, nothing else.
// ---------------------------------------------------------------------------
__global__ __launch_bounds__(512, 4) void front_kernel(
    const float* __restrict__ x, const float* __restrict__ w1,
    const float* __restrict__ b1, const float* __restrict__ w2,
    const float* __restrict__ b2, const float* __restrict__ qw,
    const float* __restrict__ hw1, const float* __restrict__ hb1,
    unsigned short* __restrict__ g) {

    __shared__ float part[8][64][33];  // 67584 B; +1 pad: conflict-free
    __shared__ float umat_s[144];      // 18 Rot matrices * 8 floats

    float (*hsh)[33] = part[0];                   // valid after reduce
    float (*casa)[12] = (float (*)[12])part[1];   // valid after angle phase

    int tid = threadIdx.x;

    // ---- phase 0: Rot matrices (covered by the enc barrier) ----------------
    if (tid < 18) {
        float phi = qw[tid * 3], theta = qw[tid * 3 + 1], omega = qw[tid * 3 + 2];
        float c = cosf(0.5f * theta), s = sinf(0.5f * theta);
        float po = 0.5f * (phi + omega), pm = 0.5f * (phi - omega);
        float epr = cosf(po), epi = -sinf(po);
        float emr = cosf(pm), emi = -sinf(pm);
        float* u = umat_s + tid * 8;
        u[0] = epr * c;  u[1] = epi * c;     // u00
        u[2] = -emr * s; u[3] = emi * s;     // u01 = -conj(em)*s
        u[4] = emr * s;  u[5] = emi * s;     // u10
        u[6] = epr * c;  u[7] = -epi * c;    // u11 = conj(ep)*c
    }

    // ---- phase 1: enc, 8-way split-K ---------------------------------------
    int lane = tid & 63;
    int wave = tid >> 6;                    // 0..7
    int swave = __builtin_amdgcn_readfirstlane(wave);
    size_t row = (size_t)blockIdx.x * 64 + lane;
    const float2* x2 = (const float2*)(x + row * 512 + swave * 64);
    const float* wseg = w1 + swave * 64 * 32;  // wave-uniform -> scalar loads

    float acc[32];
#pragma unroll
    for (int j = 0; j < 32; ++j) acc[j] = 0.f;

#pragma clang loop unroll(disable)
    for (int k2 = 0; k2 < 32; ++k2) {
        float2 xv = x2[k2];
        const float* wr = wseg + k2 * 64;
#pragma unroll
        for (int j = 0; j < 32; ++j) acc[j] = fmaf(wr[j], xv.x, acc[j]);
#pragma unroll
        for (int j = 0; j < 32; ++j) acc[j] = fmaf(wr[32 + j], xv.y, acc[j]);
    }
#pragma unroll
    for (int j = 0; j < 32; ++j) part[wave][lane][j] = acc[j];
    __syncthreads();

    // reduce 8 partials + bias + tanh -> hsh
    {
        int rl = tid & 63;
        int jg = (tid >> 6) * 4;
#pragma unroll
        for (int jj = 0; jj < 4; ++jj) {
            int j = jg + jj;
            float v = b1[j];
#pragma unroll
            for (int w = 0; w < 8; ++w) v += part[w][rl][j];
            hsh[rl][j] = tanhf(v);
        }
    }
    __syncthreads();

    // ---- phase 2: angles -> cos/sin (384 threads: 64 rows x 6 q) -----------
    if (tid < 384) {
        int row_a = tid & 63;
        int q = tid >> 6;   // 0..5
        float a = b2[q];
#pragma unroll
        for (int j = 0; j < 32; ++j) a = fmaf(hsh[row_a][j], w2[j * 6 + q], a);
        a *= 0.5f;
        casa[row_a][q * 2]     = cosf(a);
        casa[row_a][q * 2 + 1] = sinf(a);
    }
    __syncthreads();

    // ---- phase 3: circuit, 8 threads per sample ----------------------------
    int s8 = lane & 7;
    int p = lane >> 3;                  // 0..7
    int samp = wave * 8 + s8;           // 0..63
    bool pb4 = (p & 4) != 0, pb2 = (p & 2) != 0, pb1 = (p & 1) != 0;

    float ca[6], sa[6];
#pragma unroll
    for (int q = 0; q < 6; ++q) { ca[q] = casa[samp][q * 2]; sa[q] = casa[samp][q * 2 + 1]; }

    float fr[8], fi[8];
#pragma unroll
    for (int j = 0; j < 8; ++j) { fr[j] = 0.f; fi[j] = 0.f; }
    fr[0] = (p == 0) ? 1.f : 0.f;

#pragma clang loop unroll(disable)
    for (int layer = 0; layer < 3; ++layer) {
        const float* ub = umat_s + layer * 48;
#define MAT(Q)                                                            \
        const float* u = ub + (Q) * 8;                                    \
        float c = ca[Q], ss = sa[Q];                                      \
        float m00r = u[0] * c + u[2] * ss, m00i = u[1] * c + u[3] * ss;   \
        float m01r = u[2] * c - u[0] * ss, m01i = u[3] * c - u[1] * ss;   \
        float m10r = u[4] * c + u[6] * ss, m10i = u[5] * c + u[7] * ss;   \
        float m11r = u[6] * c - u[4] * ss, m11i = u[7] * c - u[5] * ss;
        { MAT(0) apply_cross<32>(fr, fi, pb4, m00r, m00i, m01r, m01i, m10r, m10i, m11r, m11i); }
        { MAT(1) apply_cross<16>(fr, fi, pb2, m00r, m00i, m01r, m01i, m10r, m10i, m11r, m11i); }
        { MAT(2) apply_cross<8>(fr, fi, pb1, m00r, m00i, m01r, m01i, m10r, m10i, m11r, m11i); }
        { MAT(3) apply_local<4>(fr, fi, m00r, m00i, m01r, m01i, m10r, m10i, m11r, m11i); }
        { MAT(4) apply_local<2>(fr, fi, m00r, m00i, m01r, m01i, m10r, m10i, m11r, m11i); }
        { MAT(5) apply_local<1>(fr, fi, m00r, m00i, m01r, m01i, m10r, m10i, m11r, m11i); }
#undef MAT
        // CNOT(0,1): control bit32 (p&4) -> flip bit16: exchange lane^16
#pragma unroll
        for (int j = 0; j < 8; ++j) {
            float pr = __shfl_xor(fr[j], 16);
            float pi = __shfl_xor(fi[j], 16);
            fr[j] = pb4 ? pr : fr[j];
            fi[j] = pb4 ? pi : fi[j];
        }
        // CNOT(2,3): control bit8 (p&1) -> flip bit4 (local j^4)
        {
            float tr[8], ti[8];
#pragma unroll
            for (int j = 0; j < 8; ++j) { tr[j] = fr[j]; ti[j] = fi[j]; }
#pragma unroll
            for (int j = 0; j < 8; ++j) {
                fr[j] = pb1 ? tr[j ^ 4] : tr[j];
                fi[j] = pb1 ? ti[j ^ 4] : ti[j];
            }
        }
        // CNOT(4,5): control bit2 (j&2) -> flip bit1
        SWAP2(2, 3) SWAP2(6, 7)
        // CNOT(1,2): control bit16 (p&2) -> flip bit8: exchange lane^8
#pragma unroll
        for (int j = 0; j < 8; ++j) {
            float pr = __shfl_xor(fr[j], 8);
            float pi = __shfl_xor(fi[j], 8);
            fr[j] = pb2 ? pr : fr[j];
            fi[j] = pb2 ? pi : fi[j];
        }
        // CNOT(3,4): control bit4 (j&4) -> flip bit2
        SWAP2(4, 6) SWAP2(5, 7)
        // CNOT(5,0): control bit1 (j odd) -> flip bit32: exchange lane^32
#pragma unroll
        for (int j = 1; j < 8; j += 2) {
            fr[j] = __shfl_xor(fr[j], 32);
            fi[j] = __shfl_xor(fi[j], 32);
        }
    }

    // ---- z expectations ----------------------------------------------------
    float zt = 0.f, z3 = 0.f, z4 = 0.f, z5 = 0.f;
#pragma unroll
    for (int j = 0; j < 8; ++j) {
        float pp = fr[j] * fr[j] + fi[j] * fi[j];
        zt += pp;
        z3 += (j & 4) ? -pp : pp;
        z4 += (j & 2) ? -pp : pp;
        z5 += (j & 1) ? -pp : pp;
    }
    float zz[6];
    zz[0] = pb4 ? -zt : zt;
    zz[1] = pb2 ? -zt : zt;
    zz[2] = pb1 ? -zt : zt;
    zz[3] = z3; zz[4] = z4; zz[5] = z5;
#pragma unroll
    for (int q = 0; q < 6; ++q) {
        zz[q] += __shfl_xor(zz[q], 8);
        zz[q] += __shfl_xor(zz[q], 16);
        zz[q] += __shfl_xor(zz[q], 32);
    }

    // ---- phase 4: head layer 1 -> g in GLOBAL (bf16, coalesced) ------------
    // Thread (samp, p) owns cols [p*16, p*16+16): same formula/order as R6.
    // Wave address set = 8 samples x 256 B fully covered -> coalesced.
    {
        unsigned short* gp = g + ((size_t)blockIdx.x * 64 + samp) * 128 + p * 16;
#pragma unroll
        for (int half = 0; half < 2; ++half) {
            ushort8 pk;
#pragma unroll
            for (int jj = 0; jj < 8; ++jj) {
                int j = p * 16 + half * 8 + jj;
                float a = hb1[j];
#pragma unroll
                for (int q = 0; q < 6; ++q) a = fmaf(zz[q], hw1[q * 128 + j], a);
                a = fmaxf(a, 0.f);
                pk[jj] = f2bf(a);
            }
            *(ushort8*)(gp + half * 8) = pk;
        }
    }
}

// ---------------------------------------------------------------------------
// K2: head GEMM v3 — out[32768][1296] = g@w2t^T + b2.
// 2048 blocks x 256 thr: 8 blocks/CU (thread-capped) = 32 waves/CU = 100%
// occupancy (mega's GEMM phase ran at 16 waves/CU, grid-locked). Each block
// owns 16 rows x all 1296 cols (write range = 648 exactly-aligned 128-B
// lines). g tile staged coalesced into 4 KB LDS with the G4 XOR swizzle,
// then bf fragments come from LDS (conflict-light ds_read_b128); af from
// L2-resident w2t. Same ks-accumulation chains as R6 -> bit-identical out.
// ---------------------------------------------------------------------------
__global__ __launch_bounds__(256) void head_gemm(
    const unsigned short* __restrict__ g, const unsigned short* __restrict__ w2t,
    const float* __restrict__ b2, float* __restrict__ out) {
    __shared__ unsigned short gl[16 * 128];   // 4 KB, swizzled

    int tid = threadIdx.x;
    int row0 = blockIdx.x * 16;               // 2048 blocks * 16 rows

    // stage: 256 thr x 16 B, coalesced global read, swizzled LDS write
    {
        int r = tid >> 4;        // 0..15 local row
        int u = tid & 15;        // 16-B unit within row
        ushort8 v = *(const ushort8*)(g + (size_t)(row0 + r) * 128 + u * 8);
        int us = u ^ (r & 7);
        *(ushort8*)(gl + r * 128 + us * 8) = v;
    }
    __syncthreads();

    int lane = tid & 63, wv = tid >> 6;       // 4 waves
    int l15 = lane & 15, quad = lane >> 4;
    int a7 = l15 & 7;

    for (int n = wv; n < 27; n += 4) {
        int col0 = n * 48;
#pragma unroll
        for (int t = 0; t < 3; ++t) {
            const unsigned short* ap =
                w2t + (size_t)(col0 + t * 16 + l15) * 128 + quad * 8;

            floatx4 acc = (floatx4)0.f;
#pragma unroll
            for (int ks = 0; ks < 4; ++ks) {
                bf16x8 af = *(const bf16x8*)(ap + ks * 32);
                int u = (quad + 4 * ks) ^ a7;
                bf16x8 bf = *(const bf16x8*)(gl + l15 * 128 + u * 8);
                acc = __builtin_amdgcn_mfma_f32_16x16x32_bf16(af, bf, acc, 0, 0, 0);
            }

            const float* bb = b2 + col0 + t * 16 + quad * 4;
            floatx4 bias = { bb[0], bb[1], bb[2], bb[3] };
            floatx4 v = acc + bias;
            *(floatx4*)(out + (size_t)(row0 + l15) * 1296 + col0 + t * 16 + quad * 4) = v;
        }
    }
}

// ---------------------------------------------------------------------------
extern "C" void kernel_launch(void* const* d_in, const int* in_sizes, int n_in,
                              void* d_out, int out_size, void* d_ws, size_t ws_size,
                              hipStream_t stream) {
    const float* x   = (const float*)d_in[0];
    const float* ew1 = (const float*)d_in[1];
    const float* eb1 = (const float*)d_in[2];
    const float* ew2 = (const float*)d_in[3];
    const float* eb2 = (const float*)d_in[4];
    const float* qw  = (const float*)d_in[5];
    const float* hw1 = (const float*)d_in[6];
    const float* hb1 = (const float*)d_in[7];
    const float* hw2 = (const float*)d_in[8];
    const float* hb2 = (const float*)d_in[9];
    float* out = (float*)d_out;

    char* ws = (char*)d_ws;
    unsigned short* g   = (unsigned short*)(ws);             // 32768*128*2 = 8388608 B
    unsigned short* w2t = (unsigned short*)(ws + 8388608);   // 1296*128*2  = 331776 B

    prep_kernel<<<dim3(41), dim3(512), 0, stream>>>(hw2, w2t);
    front_kernel<<<dim3(512), dim3(512), 0, stream>>>(
        x, ew1, eb1, ew2, eb2, qw, hw1, hb1, g);
    head_gemm<<<dim3(2048), dim3(256), 0, stream>>>(g, w2t, hb2, out);
}

// Round 8
// 364.342 us; speedup vs baseline: 1.0181x; 1.0181x over previous
//
#include <hip/hip_runtime.h>

typedef __bf16 bf16x8 __attribute__((ext_vector_type(8)));
typedef float floatx4 __attribute__((ext_vector_type(4)));
typedef unsigned short ushort8 __attribute__((ext_vector_type(8)));

__device__ __forceinline__ unsigned short f2bf(float f) {
    unsigned u = __float_as_uint(f);
    u += 0x7fffu + ((u >> 16) & 1u);   // round-to-nearest-even
    return (unsigned short)(u >> 16);
}

// ---------------------------------------------------------------------------
// Circuit helpers (verbatim from the passing R5-R7 kernels). 8-way split:
// lane = p*8 + s8; thread p holds amplitudes i = p*8 + j.
// ---------------------------------------------------------------------------
template <int ST>   // ST in {4,2,1}: thread-local gate
__device__ __forceinline__ void apply_local(float* fr, float* fi,
    float m00r, float m00i, float m01r, float m01i,
    float m10r, float m10i, float m11r, float m11i) {
#pragma unroll
    for (int i = 0; i < 8; ++i) {
        if ((i & ST) == 0) {
            int i1 = i + ST;
            float r0 = fr[i], u0 = fi[i], r1 = fr[i1], u1 = fi[i1];
            fr[i]  = m00r * r0 - m00i * u0 + m01r * r1 - m01i * u1;
            fi[i]  = m00r * u0 + m00i * r0 + m01r * u1 + m01i * r1;
            fr[i1] = m10r * r0 - m10i * u0 + m11r * r1 - m11i * u1;
            fi[i1] = m10r * u0 + m10i * r0 + m11r * u1 + m11i * r1;
        }
    }
}

template <int XM>   // XM in {32,16,8}: cross-thread gate; hi = bit=1 side
__device__ __forceinline__ void apply_cross(float* fr, float* fi, bool hi,
    float m00r, float m00i, float m01r, float m01i,
    float m10r, float m10i, float m11r, float m11i) {
    float car = hi ? m10r : m00r, cai = hi ? m10i : m00i;
    float cbr = hi ? m11r : m01r, cbi = hi ? m11i : m01i;
#pragma unroll
    for (int j = 0; j < 8; ++j) {
        float mr = fr[j], mi = fi[j];
        float pr = __shfl_xor(mr, XM);
        float pi = __shfl_xor(mi, XM);
        float a0r = hi ? pr : mr, a0i = hi ? pi : mi;
        float a1r = hi ? mr : pr, a1i = hi ? mi : pi;
        fr[j] = car * a0r - cai * a0i + cbr * a1r - cbi * a1i;
        fi[j] = car * a0i + cai * a0r + cbr * a1i + cbi * a1r;
    }
}

#define SWAP2(a, b) { float _t = fr[a]; fr[a] = fr[b]; fr[b] = _t; \
                      _t = fi[a]; fi[a] = fi[b]; fi[b] = _t; }

// ---------------------------------------------------------------------------
// K0: prep — w2t transpose + the 18 Rot matrices into global umat.
// ---------------------------------------------------------------------------
__global__ __launch_bounds__(512) void prep_kernel(
    const float* __restrict__ hw2, const float* __restrict__ qw,
    unsigned short* __restrict__ w2t, float* __restrict__ umat) {
    int t = blockIdx.x * 512 + threadIdx.x;   // 41*512 = 20992 >= 20736
    if (t < 18) {
        float phi = qw[t * 3], theta = qw[t * 3 + 1], omega = qw[t * 3 + 2];
        float c = cosf(0.5f * theta), s = sinf(0.5f * theta);
        float po = 0.5f * (phi + omega), pm = 0.5f * (phi - omega);
        float epr = cosf(po), epi = -sinf(po);
        float emr = cosf(pm), emi = -sinf(pm);
        float* u = umat + t * 8;
        u[0] = epr * c;  u[1] = epi * c;     // u00
        u[2] = -emr * s; u[3] = emi * s;     // u01 = -conj(em)*s
        u[4] = emr * s;  u[5] = emi * s;     // u10
        u[6] = epr * c;  u[7] = -epi * c;    // u11 = conj(ep)*c
    }
    int nn = t >> 4;
    int kc = (t & 15) * 8;
    if (nn < 1296) {
        ushort8 pk;
#pragma unroll
        for (int j = 0; j < 8; ++j) pk[j] = f2bf(hw2[(size_t)(kc + j) * 1296 + nn]);
        *(ushort8*)(w2t + (size_t)nn * 128 + kc) = pk;
    }
}

// ---------------------------------------------------------------------------
// K1: encoder — R0's PROVEN kernel verbatim (best-measured config).
// Block 256 = 4 waves; 64 rows/block; wave w owns k-range [w*128, w*128+128).
// Writes raw angles (pre-0.5) — the 0.5f scale is exact, applied downstream.
// ---------------------------------------------------------------------------
__global__ __launch_bounds__(256) void enc_kernel(
    const float* __restrict__ x, const float* __restrict__ w1,
    const float* __restrict__ b1, const float* __restrict__ w2,
    const float* __restrict__ b2, float* __restrict__ angles) {
    __shared__ float part[4][64][33];  // +1 pad: conflict-free
    __shared__ float hsh[64][33];
    int lane = threadIdx.x & 63;
    int wave = threadIdx.x >> 6;
    int swave = __builtin_amdgcn_readfirstlane(wave);
    size_t row = (size_t)blockIdx.x * 64 + lane;
    const float2* x2 = (const float2*)(x + row * 512 + swave * 128);
    const float* wseg = w1 + swave * 128 * 32;  // wave-uniform -> scalar

    float acc[32];
#pragma unroll
    for (int j = 0; j < 32; ++j) acc[j] = 0.f;

#pragma clang loop unroll(disable)
    for (int k2 = 0; k2 < 64; ++k2) {
        float2 xv = x2[k2];
        const float* wr = wseg + k2 * 64;
#pragma unroll
        for (int j = 0; j < 32; ++j) acc[j] = fmaf(wr[j], xv.x, acc[j]);
#pragma unroll
        for (int j = 0; j < 32; ++j) acc[j] = fmaf(wr[32 + j], xv.y, acc[j]);
    }
#pragma unroll
    for (int j = 0; j < 32; ++j) part[wave][lane][j] = acc[j];
    __syncthreads();

    int rl = threadIdx.x & 63;
    int jg = (threadIdx.x >> 6) * 8;
#pragma unroll
    for (int jj = 0; jj < 8; ++jj) {
        int j = jg + jj;
        float v = part[0][rl][j] + part[1][rl][j] + part[2][rl][j] + part[3][rl][j] + b1[j];
        hsh[rl][j] = tanhf(v);
    }
    __syncthreads();

    if (threadIdx.x < 64) {
        float h[32];
#pragma unroll
        for (int j = 0; j < 32; ++j) h[j] = hsh[threadIdx.x][j];
#pragma unroll
        for (int q = 0; q < 6; ++q) {
            float a = b2[q];
#pragma unroll
            for (int j = 0; j < 32; ++j) a = fmaf(h[j], w2[j * 6 + q], a);
            angles[((size_t)blockIdx.x * 64 + threadIdx.x) * 6 + q] = a;
        }
    }
}

// ---------------------------------------------------------------------------
// K2: circuit — BARRIER-FREE, LDS-FREE. 256 thr x 1024 blocks, 8 thr/sample,
// 32 samples/block. umat + angles read from L2-hot global; cos/sin computed
// per-thread (12 transcendentals, redundant x8 — cheap). Writes z fp32
// (768 KB, vs the old 8 MB g). Pure dataflow: waves never wait on each other.
// ---------------------------------------------------------------------------
__global__ __launch_bounds__(256) void circuit_kernel(
    const float* __restrict__ angles, const float* __restrict__ umat,
    float* __restrict__ z) {
    int tid = threadIdx.x;
    int lane = tid & 63;
    int wv = tid >> 6;                     // 0..3
    int s8 = lane & 7;
    int p = lane >> 3;                     // 0..7
    int samp = blockIdx.x * 32 + wv * 8 + s8;   // 1024 blocks * 32 samples
    bool pb4 = (p & 4) != 0, pb2 = (p & 2) != 0, pb1 = (p & 1) != 0;

    float ca[6], sa[6];
#pragma unroll
    for (int q = 0; q < 6; ++q) {
        float a = 0.5f * angles[(size_t)samp * 6 + q];
        ca[q] = cosf(a);
        sa[q] = sinf(a);
    }

    float fr[8], fi[8];
#pragma unroll
    for (int j = 0; j < 8; ++j) { fr[j] = 0.f; fi[j] = 0.f; }
    fr[0] = (p == 0) ? 1.f : 0.f;

#pragma clang loop unroll(disable)
    for (int layer = 0; layer < 3; ++layer) {
        const float* ub = umat + layer * 48;
#define MAT(Q)                                                            \
        const float* u = ub + (Q) * 8;                                    \
        float c = ca[Q], ss = sa[Q];                                      \
        float m00r = u[0] * c + u[2] * ss, m00i = u[1] * c + u[3] * ss;   \
        float m01r = u[2] * c - u[0] * ss, m01i = u[3] * c - u[1] * ss;   \
        float m10r = u[4] * c + u[6] * ss, m10i = u[5] * c + u[7] * ss;   \
        float m11r = u[6] * c - u[4] * ss, m11i = u[7] * c - u[5] * ss;
        { MAT(0) apply_cross<32>(fr, fi, pb4, m00r, m00i, m01r, m01i, m10r, m10i, m11r, m11i); }
        { MAT(1) apply_cross<16>(fr, fi, pb2, m00r, m00i, m01r, m01i, m10r, m10i, m11r, m11i); }
        { MAT(2) apply_cross<8>(fr, fi, pb1, m00r, m00i, m01r, m01i, m10r, m10i, m11r, m11i); }
        { MAT(3) apply_local<4>(fr, fi, m00r, m00i, m01r, m01i, m10r, m10i, m11r, m11i); }
        { MAT(4) apply_local<2>(fr, fi, m00r, m00i, m01r, m01i, m10r, m10i, m11r, m11i); }
        { MAT(5) apply_local<1>(fr, fi, m00r, m00i, m01r, m01i, m10r, m10i, m11r, m11i); }
#undef MAT
        // CNOT(0,1): control bit32 (p&4) -> flip bit16: exchange lane^16
#pragma unroll
        for (int j = 0; j < 8; ++j) {
            float pr = __shfl_xor(fr[j], 16);
            float pi = __shfl_xor(fi[j], 16);
            fr[j] = pb4 ? pr : fr[j];
            fi[j] = pb4 ? pi : fi[j];
        }
        // CNOT(2,3): control bit8 (p&1) -> flip bit4 (local j^4)
        {
            float tr[8], ti[8];
#pragma unroll
            for (int j = 0; j < 8; ++j) { tr[j] = fr[j]; ti[j] = fi[j]; }
#pragma unroll
            for (int j = 0; j < 8; ++j) {
                fr[j] = pb1 ? tr[j ^ 4] : tr[j];
                fi[j] = pb1 ? ti[j ^ 4] : ti[j];
            }
        }
        // CNOT(4,5): control bit2 (j&2) -> flip bit1
        SWAP2(2, 3) SWAP2(6, 7)
        // CNOT(1,2): control bit16 (p&2) -> flip bit8: exchange lane^8
#pragma unroll
        for (int j = 0; j < 8; ++j) {
            float pr = __shfl_xor(fr[j], 8);
            float pi = __shfl_xor(fi[j], 8);
            fr[j] = pb2 ? pr : fr[j];
            fi[j] = pb2 ? pi : fi[j];
        }
        // CNOT(3,4): control bit4 (j&4) -> flip bit2
        SWAP2(4, 6) SWAP2(5, 7)
        // CNOT(5,0): control bit1 (j odd) -> flip bit32: exchange lane^32
#pragma unroll
        for (int j = 1; j < 8; j += 2) {
            fr[j] = __shfl_xor(fr[j], 32);
            fi[j] = __shfl_xor(fi[j], 32);
        }
    }

    // z expectations: per-thread partials, butterfly over the 8 parts
    float zt = 0.f, z3 = 0.f, z4 = 0.f, z5 = 0.f;
#pragma unroll
    for (int j = 0; j < 8; ++j) {
        float pp = fr[j] * fr[j] + fi[j] * fi[j];
        zt += pp;
        z3 += (j & 4) ? -pp : pp;
        z4 += (j & 2) ? -pp : pp;
        z5 += (j & 1) ? -pp : pp;
    }
    float zz[6];
    zz[0] = pb4 ? -zt : zt;
    zz[1] = pb2 ? -zt : zt;
    zz[2] = pb1 ? -zt : zt;
    zz[3] = z3; zz[4] = z4; zz[5] = z5;
#pragma unroll
    for (int q = 0; q < 6; ++q) {
        zz[q] += __shfl_xor(zz[q], 8);
        zz[q] += __shfl_xor(zz[q], 16);
        zz[q] += __shfl_xor(zz[q], 32);
    }
    if (p < 6) z[(size_t)samp * 6 + p] = zz[p];
}

// ---------------------------------------------------------------------------
// K3: head GEMM v4 — computes the g-tile from z IN-BLOCK (g never exists in
// global), then the R7-proven MFMA loop. 2048 blocks x 256 thr, ~4.4 KB LDS
// -> 8 blocks/CU = 100% occupancy. Block writes 16 rows x 1296 cols = 648
// exactly-aligned 128-B lines.
// ---------------------------------------------------------------------------
__global__ __launch_bounds__(256) void head_gemm(
    const float* __restrict__ z, const unsigned short* __restrict__ w2t,
    const float* __restrict__ hw1, const float* __restrict__ hb1,
    const float* __restrict__ b2, float* __restrict__ out) {
    __shared__ unsigned short gl[16 * 128];   // 4 KB, swizzled
    __shared__ float zsh[16][6];

    int tid = threadIdx.x;
    int row0 = blockIdx.x * 16;               // 2048 blocks * 16 rows

    if (tid < 96) zsh[tid / 6][tid % 6] = z[(size_t)row0 * 6 + tid];
    __syncthreads();

    // g tile: row r = tid>>4, cols [ (tid&15)*8, +8 ). Same fp32 formula/
    // order + f2bf as every passing kernel -> identical bits.
    {
        int r = tid >> 4;        // 0..15
        int u = tid & 15;        // 16-B unit within the row
        int j0 = u * 8;
        float zr[6];
#pragma unroll
        for (int q = 0; q < 6; ++q) zr[q] = zsh[r][q];
        ushort8 pk;
#pragma unroll
        for (int jj = 0; jj < 8; ++jj) {
            int j = j0 + jj;
            float a = hb1[j];
#pragma unroll
            for (int q = 0; q < 6; ++q) a = fmaf(zr[q], hw1[q * 128 + j], a);
            a = fmaxf(a, 0.f);
            pk[jj] = f2bf(a);
        }
        int us = u ^ (r & 7);
        *(ushort8*)(gl + r * 128 + us * 8) = pk;
    }
    __syncthreads();

    int lane = tid & 63, wv = tid >> 6;       // 4 waves
    int l15 = lane & 15, quad = lane >> 4;
    int a7 = l15 & 7;

    for (int n = wv; n < 27; n += 4) {
        int col0 = n * 48;
#pragma unroll
        for (int t = 0; t < 3; ++t) {
            const unsigned short* ap =
                w2t + (size_t)(col0 + t * 16 + l15) * 128 + quad * 8;

            floatx4 acc = (floatx4)0.f;
#pragma unroll
            for (int ks = 0; ks < 4; ++ks) {
                bf16x8 af = *(const bf16x8*)(ap + ks * 32);
                int u = (quad + 4 * ks) ^ a7;
                bf16x8 bf = *(const bf16x8*)(gl + l15 * 128 + u * 8);
                acc = __builtin_amdgcn_mfma_f32_16x16x32_bf16(af, bf, acc, 0, 0, 0);
            }

            const float* bb = b2 + col0 + t * 16 + quad * 4;
            floatx4 bias = { bb[0], bb[1], bb[2], bb[3] };
            floatx4 v = acc + bias;
            *(floatx4*)(out + (size_t)(row0 + l15) * 1296 + col0 + t * 16 + quad * 4) = v;
        }
    }
}

// ---------------------------------------------------------------------------
extern "C" void kernel_launch(void* const* d_in, const int* in_sizes, int n_in,
                              void* d_out, int out_size, void* d_ws, size_t ws_size,
                              hipStream_t stream) {
    const float* x   = (const float*)d_in[0];
    const float* ew1 = (const float*)d_in[1];
    const float* eb1 = (const float*)d_in[2];
    const float* ew2 = (const float*)d_in[3];
    const float* eb2 = (const float*)d_in[4];
    const float* qw  = (const float*)d_in[5];
    const float* hw1 = (const float*)d_in[6];
    const float* hb1 = (const float*)d_in[7];
    const float* hw2 = (const float*)d_in[8];
    const float* hb2 = (const float*)d_in[9];
    float* out = (float*)d_out;

    char* ws = (char*)d_ws;
    unsigned short* w2t = (unsigned short*)(ws);        // 331776 B
    float* umat   = (float*)(ws + 331776);              // 576 B
    float* angles = (float*)(ws + 332352);              // 786432 B
    float* z      = (float*)(ws + 1118784);             // 786432 B

    prep_kernel<<<dim3(41), dim3(512), 0, stream>>>(hw2, qw, w2t, umat);
    enc_kernel<<<dim3(512), dim3(256), 0, stream>>>(x, ew1, eb1, ew2, eb2, angles);
    circuit_kernel<<<dim3(1024), dim3(256), 0, stream>>>(angles, umat, z);
    head_gemm<<<dim3(2048), dim3(256), 0, stream>>>(z, w2t, hw1, hb1, hb2, out);
}

// Round 9
// 361.220 us; speedup vs baseline: 1.0269x; 1.0086x over previous
//
#include <hip/hip_runtime.h>

typedef __bf16 bf16x8 __attribute__((ext_vector_type(8)));
typedef float floatx4 __attribute__((ext_vector_type(4)));
typedef unsigned short ushort8 __attribute__((ext_vector_type(8)));

__device__ __forceinline__ unsigned short f2bf(float f) {
    unsigned u = __float_as_uint(f);
    u += 0x7fffu + ((u >> 16) & 1u);   // round-to-nearest-even
    return (unsigned short)(u >> 16);
}

// ---------------------------------------------------------------------------
// K0: prep — w2t transpose + the 18 Rot matrices into global umat.
// ---------------------------------------------------------------------------
__global__ __launch_bounds__(512) void prep_kernel(
    const float* __restrict__ hw2, const float* __restrict__ qw,
    unsigned short* __restrict__ w2t, float* __restrict__ umat) {
    int t = blockIdx.x * 512 + threadIdx.x;   // 41*512 = 20992 >= 20736
    if (t < 18) {
        float phi = qw[t * 3], theta = qw[t * 3 + 1], omega = qw[t * 3 + 2];
        float c = cosf(0.5f * theta), s = sinf(0.5f * theta);
        float po = 0.5f * (phi + omega), pm = 0.5f * (phi - omega);
        float epr = cosf(po), epi = -sinf(po);
        float emr = cosf(pm), emi = -sinf(pm);
        float* u = umat + t * 8;
        u[0] = epr * c;  u[1] = epi * c;     // u00
        u[2] = -emr * s; u[3] = emi * s;     // u01 = -conj(em)*s
        u[4] = emr * s;  u[5] = emi * s;     // u10
        u[6] = epr * c;  u[7] = -epi * c;    // u11 = conj(ep)*c
    }
    int nn = t >> 4;
    int kc = (t & 15) * 8;
    if (nn < 1296) {
        ushort8 pk;
#pragma unroll
        for (int j = 0; j < 8; ++j) pk[j] = f2bf(hw2[(size_t)(kc + j) * 1296 + nn]);
        *(ushort8*)(w2t + (size_t)nn * 128 + kc) = pk;
    }
}

// ---------------------------------------------------------------------------
// K1: encoder — R0's PROVEN kernel verbatim (best-measured config).
// Block 256 = 4 waves; 64 rows/block; wave w owns k-range [w*128, w*128+128).
// ---------------------------------------------------------------------------
__global__ __launch_bounds__(256) void enc_kernel(
    const float* __restrict__ x, const float* __restrict__ w1,
    const float* __restrict__ b1, const float* __restrict__ w2,
    const float* __restrict__ b2, float* __restrict__ angles) {
    __shared__ float part[4][64][33];  // +1 pad: conflict-free
    __shared__ float hsh[64][33];
    int lane = threadIdx.x & 63;
    int wave = threadIdx.x >> 6;
    int swave = __builtin_amdgcn_readfirstlane(wave);
    size_t row = (size_t)blockIdx.x * 64 + lane;
    const float2* x2 = (const float2*)(x + row * 512 + swave * 128);
    const float* wseg = w1 + swave * 128 * 32;  // wave-uniform -> scalar

    float acc[32];
#pragma unroll
    for (int j = 0; j < 32; ++j) acc[j] = 0.f;

#pragma clang loop unroll(disable)
    for (int k2 = 0; k2 < 64; ++k2) {
        float2 xv = x2[k2];
        const float* wr = wseg + k2 * 64;
#pragma unroll
        for (int j = 0; j < 32; ++j) acc[j] = fmaf(wr[j], xv.x, acc[j]);
#pragma unroll
        for (int j = 0; j < 32; ++j) acc[j] = fmaf(wr[32 + j], xv.y, acc[j]);
    }
#pragma unroll
    for (int j = 0; j < 32; ++j) part[wave][lane][j] = acc[j];
    __syncthreads();

    int rl = threadIdx.x & 63;
    int jg = (threadIdx.x >> 6) * 8;
#pragma unroll
    for (int jj = 0; jj < 8; ++jj) {
        int j = jg + jj;
        float v = part[0][rl][j] + part[1][rl][j] + part[2][rl][j] + part[3][rl][j] + b1[j];
        hsh[rl][j] = tanhf(v);
    }
    __syncthreads();

    if (threadIdx.x < 64) {
        float h[32];
#pragma unroll
        for (int j = 0; j < 32; ++j) h[j] = hsh[threadIdx.x][j];
#pragma unroll
        for (int q = 0; q < 6; ++q) {
            float a = b2[q];
#pragma unroll
            for (int j = 0; j < 32; ++j) a = fmaf(h[j], w2[j * 6 + q], a);
            angles[((size_t)blockIdx.x * 64 + threadIdx.x) * 6 + q] = a;
        }
    }
}

// ---------------------------------------------------------------------------
// K2: quantum — R0's PROVEN one-sample-per-thread kernel (full 64-amp state
// in registers, massive ILP) MINUS the z->g head (which was ~900 serial VALU
// per thread at 0.5 waves/SIMD — worst placement). Writes z fp32 (768 KB)
// instead of g (8 MB). z arithmetic verbatim from R0 (bit-identical).
// ---------------------------------------------------------------------------
template <int ST>
__device__ __forceinline__ void apply_g(float* sr, float* si,
    float m00r, float m00i, float m01r, float m01i,
    float m10r, float m10i, float m11r, float m11i) {
#pragma unroll
    for (int i = 0; i < 64; ++i) {
        if ((i & ST) == 0) {
            int i1 = i + ST;
            float r0 = sr[i], u0 = si[i], r1 = sr[i1], u1 = si[i1];
            sr[i]  = m00r * r0 - m00i * u0 + m01r * r1 - m01i * u1;
            si[i]  = m00r * u0 + m00i * r0 + m01r * u1 + m01i * r1;
            sr[i1] = m10r * r0 - m10i * u0 + m11r * r1 - m11i * u1;
            si[i1] = m10r * u0 + m10i * r0 + m11r * u1 + m11i * r1;
        }
    }
}

template <int CB, int TB>
__device__ __forceinline__ void cnot_g(float* sr, float* si) {
#pragma unroll
    for (int i = 0; i < 64; ++i) {
        if ((i & CB) && !(i & TB)) {
            int i1 = i + TB;
            float tr = sr[i]; sr[i] = sr[i1]; sr[i1] = tr;
            float ti = si[i]; si[i] = si[i1]; si[i1] = ti;
        }
    }
}

__global__ __launch_bounds__(64) void quantum_kernel(
    const float* __restrict__ angles, const float* __restrict__ umat,
    float* __restrict__ z) {
    int s = blockIdx.x * 64 + threadIdx.x;
    float ca[6], sa[6];
#pragma unroll
    for (int q = 0; q < 6; ++q) {
        float a = 0.5f * angles[(size_t)s * 6 + q];
        ca[q] = cosf(a);
        sa[q] = sinf(a);
    }
    float sr[64], si[64];
#pragma unroll
    for (int i = 0; i < 64; ++i) { sr[i] = 0.f; si[i] = 0.f; }
    sr[0] = 1.f;

#pragma clang loop unroll(disable)
    for (int layer = 0; layer < 3; ++layer) {
        const float* ub = umat + layer * 48;
#define DOQ(Q, ST) {                                                      \
        const float* u = ub + (Q) * 8;                                    \
        float c = ca[Q], ss = sa[Q];                                      \
        float m00r = u[0] * c + u[2] * ss, m00i = u[1] * c + u[3] * ss;   \
        float m01r = u[2] * c - u[0] * ss, m01i = u[3] * c - u[1] * ss;   \
        float m10r = u[4] * c + u[6] * ss, m10i = u[5] * c + u[7] * ss;   \
        float m11r = u[6] * c - u[4] * ss, m11i = u[7] * c - u[5] * ss;   \
        apply_g<ST>(sr, si, m00r, m00i, m01r, m01i, m10r, m10i, m11r, m11i); }
        DOQ(0, 32) DOQ(1, 16) DOQ(2, 8) DOQ(3, 4) DOQ(4, 2) DOQ(5, 1)
#undef DOQ
        cnot_g<32, 16>(sr, si);  // CNOT(0,1)
        cnot_g<8, 4>(sr, si);    // CNOT(2,3)
        cnot_g<2, 1>(sr, si);    // CNOT(4,5)
        cnot_g<16, 8>(sr, si);   // CNOT(1,2)
        cnot_g<4, 2>(sr, si);    // CNOT(3,4)
        cnot_g<1, 32>(sr, si);   // CNOT(5,0)
    }

    float zz[6] = {0.f, 0.f, 0.f, 0.f, 0.f, 0.f};
#pragma unroll
    for (int i = 0; i < 64; ++i) {
        float p = sr[i] * sr[i] + si[i] * si[i];
        zz[0] += (i & 32) ? -p : p;
        zz[1] += (i & 16) ? -p : p;
        zz[2] += (i & 8)  ? -p : p;
        zz[3] += (i & 4)  ? -p : p;
        zz[4] += (i & 2)  ? -p : p;
        zz[5] += (i & 1)  ? -p : p;
    }
#pragma unroll
    for (int q = 0; q < 6; ++q) z[(size_t)s * 6 + q] = zz[q];
}

// ---------------------------------------------------------------------------
// K3: head GEMM v4 — R8 PROVEN verbatim. Computes the g-tile from z IN-BLOCK
// (g never exists in global), then MFMA. 2048 blocks x 256 thr, ~4.4 KB LDS
// -> 8 blocks/CU = 32 waves/CU. Block writes 16 rows x 1296 cols = 648
// exactly-aligned 128-B lines.
// ---------------------------------------------------------------------------
__global__ __launch_bounds__(256) void head_gemm(
    const float* __restrict__ z, const unsigned short* __restrict__ w2t,
    const float* __restrict__ hw1, const float* __restrict__ hb1,
    const float* __restrict__ b2, float* __restrict__ out) {
    __shared__ unsigned short gl[16 * 128];   // 4 KB, swizzled
    __shared__ float zsh[16][6];

    int tid = threadIdx.x;
    int row0 = blockIdx.x * 16;               // 2048 blocks * 16 rows

    if (tid < 96) zsh[tid / 6][tid % 6] = z[(size_t)row0 * 6 + tid];
    __syncthreads();

    // g tile: row r = tid>>4, cols [(tid&15)*8, +8). Same fp32 formula/order
    // + f2bf as every passing kernel -> identical bits.
    {
        int r = tid >> 4;        // 0..15
        int u = tid & 15;        // 16-B unit within the row
        int j0 = u * 8;
        float zr[6];
#pragma unroll
        for (int q = 0; q < 6; ++q) zr[q] = zsh[r][q];
        ushort8 pk;
#pragma unroll
        for (int jj = 0; jj < 8; ++jj) {
            int j = j0 + jj;
            float a = hb1[j];
#pragma unroll
            for (int q = 0; q < 6; ++q) a = fmaf(zr[q], hw1[q * 128 + j], a);
            a = fmaxf(a, 0.f);
            pk[jj] = f2bf(a);
        }
        int us = u ^ (r & 7);
        *(ushort8*)(gl + r * 128 + us * 8) = pk;
    }
    __syncthreads();

    int lane = tid & 63, wv = tid >> 6;       // 4 waves
    int l15 = lane & 15, quad = lane >> 4;
    int a7 = l15 & 7;

    for (int n = wv; n < 27; n += 4) {
        int col0 = n * 48;
#pragma unroll
        for (int t = 0; t < 3; ++t) {
            const unsigned short* ap =
                w2t + (size_t)(col0 + t * 16 + l15) * 128 + quad * 8;

            floatx4 acc = (floatx4)0.f;
#pragma unroll
            for (int ks = 0; ks < 4; ++ks) {
                bf16x8 af = *(const bf16x8*)(ap + ks * 32);
                int u = (quad + 4 * ks) ^ a7;
                bf16x8 bf = *(const bf16x8*)(gl + l15 * 128 + u * 8);
                acc = __builtin_amdgcn_mfma_f32_16x16x32_bf16(af, bf, acc, 0, 0, 0);
            }

            const float* bb = b2 + col0 + t * 16 + quad * 4;
            floatx4 bias = { bb[0], bb[1], bb[2], bb[3] };
            floatx4 v = acc + bias;
            *(floatx4*)(out + (size_t)(row0 + l15) * 1296 + col0 + t * 16 + quad * 4) = v;
        }
    }
}

// ---------------------------------------------------------------------------
extern "C" void kernel_launch(void* const* d_in, const int* in_sizes, int n_in,
                              void* d_out, int out_size, void* d_ws, size_t ws_size,
                              hipStream_t stream) {
    const float* x   = (const float*)d_in[0];
    const float* ew1 = (const float*)d_in[1];
    const float* eb1 = (const float*)d_in[2];
    const float* ew2 = (const float*)d_in[3];
    const float* eb2 = (const float*)d_in[4];
    const float* qw  = (const float*)d_in[5];
    const float* hw1 = (const float*)d_in[6];
    const float* hb1 = (const float*)d_in[7];
    const float* hw2 = (const float*)d_in[8];
    const float* hb2 = (const float*)d_in[9];
    float* out = (float*)d_out;

    char* ws = (char*)d_ws;
    unsigned short* w2t = (unsigned short*)(ws);        // 331776 B
    float* umat   = (float*)(ws + 331776);              // 576 B
    float* angles = (float*)(ws + 332352);              // 786432 B
    float* z      = (float*)(ws + 1118784);             // 786432 B

    prep_kernel<<<dim3(41), dim3(512), 0, stream>>>(hw2, qw, w2t, umat);
    enc_kernel<<<dim3(512), dim3(256), 0, stream>>>(x, ew1, eb1, ew2, eb2, angles);
    quantum_kernel<<<dim3(512), dim3(64), 0, stream>>>(angles, umat, z);
    head_gemm<<<dim3(2048), dim3(256), 0, stream>>>(z, w2t, hw1, hb1, hb2, out);
}